// Round 4
// baseline (284.726 us; speedup 1.0000x reference)
//
#include <hip/hip_runtime.h>
#include <hip/hip_bf16.h>

typedef __attribute__((ext_vector_type(8))) short short8;
typedef __attribute__((ext_vector_type(4))) short short4_t;
typedef __attribute__((ext_vector_type(4))) float floatx4;
typedef unsigned short u16;
typedef unsigned int u32;

#define SEQ 2048
#define NH 16
#define HD 64
#define CDIM 1024
#define MTOT 8192

// RNE fp32 -> bf16
__device__ __forceinline__ u16 f2bf(float f) {
  u32 u = __builtin_bit_cast(u32, f);
  u32 r = u + 0x7FFFu + ((u >> 16) & 1u);
  return (u16)(r >> 16);
}

__device__ __forceinline__ void gload16(const void* g, void* l) {
  __builtin_amdgcn_global_load_lds(
      (const __attribute__((address_space(1))) u32*)g,
      (__attribute__((address_space(3))) u32*)l, 16, 0, 0);
}

// ---------------- convert x: fp32 -> bf16, 8 elems/thread ----------------
__global__ void cvt_x_kernel(const float* __restrict__ x, u16* __restrict__ xb) {
  size_t i = (size_t)blockIdx.x * 256 + threadIdx.x;
  const float4* xv = (const float4*)x;
  float4 a = xv[2 * i], c = xv[2 * i + 1];
  union { u16 h[8]; short8 v; } u;
  u.h[0] = f2bf(a.x); u.h[1] = f2bf(a.y); u.h[2] = f2bf(a.z); u.h[3] = f2bf(a.w);
  u.h[4] = f2bf(c.x); u.h[5] = f2bf(c.y); u.h[6] = f2bf(c.z); u.h[7] = f2bf(c.w);
  *(short8*)(xb + 8 * i) = u.v;
}

// ------------- transpose W [K][N] fp32 -> WT [N][K] bf16 -------------
__global__ void transpose_w(const float* __restrict__ w, u16* __restrict__ wt,
                            int K, int N) {
  __shared__ float t[32][33];
  int n0 = blockIdx.x * 32, k0 = blockIdx.y * 32;
  int tr = threadIdx.x >> 5, tc = threadIdx.x & 31;
#pragma unroll
  for (int i = 0; i < 4; i++) {
    int r = tr + i * 8;
    t[r][tc] = w[(size_t)(k0 + r) * N + n0 + tc];
  }
  __syncthreads();
#pragma unroll
  for (int i = 0; i < 4; i++) {
    int r = tr + i * 8;
    wt[(size_t)(n0 + r) * K + k0 + tc] = f2bf(t[tc][r]);
  }
}

// ---- gemm_qkv v2: 256x256xBK64 8-phase (T3+T4), 8 waves (2Mx4N), 512 thr ----
// m97-structure pipelining grafts are measured nulls (m99/m100/m131/m139);
// only the 8-phase 256^2 schedule breaks the ~900TF ceiling (m196-m218).
// Structure per K-tile: burst-issue next tile's 8 gload16 -> counted
// vmcnt(8) (old 8 landed, new 8 stay in flight across the RAW barrier; never
// drain to 0 in main loop) -> 4 quadrant phases, each {12 ds_read_b128;
// s_barrier; lgkmcnt(0); sched_barrier; setprio(1); 16 MFMA; setprio(0);
// s_barrier}. Fragment/swizzle math identical to the verified 128^2 kernel.
// __launch_bounds__(512,1): 2nd arg = min BLOCKS/CU on hipcc (R2 finding),
// 1 blk x 8 waves -> 256-VGPR cap, no spill at ~210 VGPR.
__global__ __launch_bounds__(512, 1) void gemm_qkv(
    const u16* __restrict__ A, const u16* __restrict__ BT,
    u16* __restrict__ qb, u16* __restrict__ kb, u16* __restrict__ vtb) {
  __shared__ char smem[131072];  // A: [0,64K) 2 dbuf x 32KB; B: [64K,128K)
  const int tid = threadIdx.x;
  const int w = tid >> 6, l = tid & 63;
  const int quad = l >> 4, l15 = l & 15;
  const int m0 = blockIdx.x * 256, n0 = blockIdx.y * 256;
  const int wr = w >> 2, wc = w & 3;  // 2 M-waves x 4 N-waves; per-wave 128x64

  floatx4 acc[8][4] = {};

  auto stage = [&](int kt, int d) {
    char* Ad = smem + d * 32768;
    char* Bd = smem + 65536 + d * 32768;
#pragma unroll
    for (int rnd = 0; rnd < 4; rnd++) {
      int ci = rnd * 512 + tid;
      int r = ci >> 3, pos = ci & 7;
      int c = pos ^ (r & 7);
      gload16(A + (size_t)(m0 + r) * 1024 + kt * 64 + c * 8, Ad + ci * 16);
      gload16(BT + (size_t)(n0 + r) * 1024 + kt * 64 + c * 8, Bd + ci * 16);
    }
  };

  stage(0, 0);

  for (int kt = 0; kt < 16; ++kt) {
    const int cur = kt & 1;
    if (kt < 15) stage(kt + 1, cur ^ 1);
    __builtin_amdgcn_sched_barrier(0);
    if (kt < 15) asm volatile("s_waitcnt vmcnt(8)" ::: "memory");
    else         asm volatile("s_waitcnt vmcnt(0)" ::: "memory");
    __builtin_amdgcn_s_barrier();
    __builtin_amdgcn_sched_barrier(0);
    char* Ab_ = smem + cur * 32768;
    char* Bb_ = smem + 65536 + cur * 32768;
#pragma unroll
    for (int ph = 0; ph < 4; ++ph) {
      const int mh = ph >> 1, nh = ph & 1;
      short8 af[4][2], bf[2][2];
#pragma unroll
      for (int i = 0; i < 4; i++) {
        int ra = wr * 128 + mh * 64 + i * 16 + l15;
        int ga = ra & 7;
#pragma unroll
        for (int ks = 0; ks < 2; ks++)
          af[i][ks] = *(short8*)(Ab_ + ra * 128 + ((ks * 4 + quad) ^ ga) * 16);
      }
#pragma unroll
      for (int j = 0; j < 2; j++) {
        int rb = wc * 64 + (nh * 2 + j) * 16 + l15;
        int gb = rb & 7;
#pragma unroll
        for (int ks = 0; ks < 2; ks++)
          bf[j][ks] = *(short8*)(Bb_ + rb * 128 + ((ks * 4 + quad) ^ gb) * 16);
      }
      __builtin_amdgcn_s_barrier();
      asm volatile("s_waitcnt lgkmcnt(0)" ::: "memory");
      __builtin_amdgcn_sched_barrier(0);
      __builtin_amdgcn_s_setprio(1);
#pragma unroll
      for (int ks = 0; ks < 2; ks++)
#pragma unroll
        for (int i = 0; i < 4; i++)
#pragma unroll
          for (int j = 0; j < 2; j++)
            acc[mh * 4 + i][nh * 2 + j] = __builtin_amdgcn_mfma_f32_16x16x32_bf16(
                af[i][ks], bf[j][ks], acc[mh * 4 + i][nh * 2 + j], 0, 0, 0);
      __builtin_amdgcn_s_setprio(0);
      __builtin_amdgcn_s_barrier();
      __builtin_amdgcn_sched_barrier(0);
    }
  }

  // epilogue: q pre-scaled by 0.125*log2(e) (exp2 folding), k -> [bh][n][d];
  // v -> transposed [bh][d][n]
#pragma unroll
  for (int i = 0; i < 8; i++)
#pragma unroll
    for (int j = 0; j < 4; j++)
#pragma unroll
      for (int r = 0; r < 4; r++) {
        int m = m0 + wr * 128 + i * 16 + quad * 4 + r;
        int c = n0 + wc * 64 + j * 16 + l15;
        int b = m >> 11, n = m & 2047;
        int t = c >> 10, rem = c & 1023;
        int h = rem >> 6, d = rem & 63;
        int bh = b * NH + h;
        if (t == 0)      qb[((size_t)bh * SEQ + n) * HD + d] = f2bf(acc[i][j][r] * 0.18033688011112042f);
        else if (t == 1) kb[((size_t)bh * SEQ + n) * HD + d] = f2bf(acc[i][j][r]);
        else             vtb[((size_t)bh * HD + d) * SEQ + n] = f2bf(acc[i][j][r]);
      }
}

__global__ __launch_bounds__(256, 2) void gemm_proj(
    const u16* __restrict__ A, const u16* __restrict__ BT,
    const float* __restrict__ bias, float* __restrict__ out) {
  __shared__ u16 Ab[128 * 64];
  __shared__ u16 Bb[128 * 64];
  const int tid = threadIdx.x;
  const int w = tid >> 6, l = tid & 63;
  const int quad = l >> 4, l15 = l & 15;
  const int m0 = blockIdx.x * 128, n0 = blockIdx.y * 128;
  const int wr = w >> 1, wc = w & 1;

  floatx4 acc[4][4] = {};

  for (int k0 = 0; k0 < 1024; k0 += 64) {
    __syncthreads();
#pragma unroll
    for (int rnd = 0; rnd < 4; rnd++) {
      int ci = rnd * 256 + tid;
      int r = ci >> 3, pos = ci & 7;
      int c = pos ^ (r & 7);
      gload16(A + (size_t)(m0 + r) * 1024 + k0 + c * 8, (char*)Ab + ci * 16);
      gload16(BT + (size_t)(n0 + r) * 1024 + k0 + c * 8, (char*)Bb + ci * 16);
    }
    __syncthreads();
    short8 af[4][2], bf[4][2];
#pragma unroll
    for (int t = 0; t < 4; t++) {
      int ra = wr * 64 + t * 16 + l15;
      int ga = ra & 7;
#pragma unroll
      for (int ks = 0; ks < 2; ks++)
        af[t][ks] = *(short8*)((char*)Ab + ra * 128 + ((ks * 4 + quad) ^ ga) * 16);
      int rb = wc * 64 + t * 16 + l15;
      int gb = rb & 7;
#pragma unroll
      for (int ks = 0; ks < 2; ks++)
        bf[t][ks] = *(short8*)((char*)Bb + rb * 128 + ((ks * 4 + quad) ^ gb) * 16);
    }
#pragma unroll
    for (int ks = 0; ks < 2; ks++)
#pragma unroll
      for (int i = 0; i < 4; i++)
#pragma unroll
        for (int j = 0; j < 4; j++)
          acc[i][j] = __builtin_amdgcn_mfma_f32_16x16x32_bf16(af[i][ks], bf[j][ks], acc[i][j], 0, 0, 0);
  }

#pragma unroll
  for (int i = 0; i < 4; i++)
#pragma unroll
    for (int j = 0; j < 4; j++)
#pragma unroll
      for (int r = 0; r < 4; r++) {
        int m = m0 + wr * 64 + i * 16 + quad * 4 + r;
        int c = n0 + wc * 64 + j * 16 + l15;
        out[(size_t)m * CDIM + c] = acc[i][j][r] + bias[c];
      }
}

// ---- flash attention v5 (verified 72.3us): 8 waves x 32 Q-rows, 16 waves/CU ----
// R3: T5 setprio was null-to-negative (74.1 vs 72.3) -> removed. attn is at
// its plain-HIP structural plateau (~950 TF effective).
__global__ __launch_bounds__(512, 4) void attn_kernel(
    const u16* __restrict__ Qb, const u16* __restrict__ Kb,
    const u16* __restrict__ Vtb, u16* __restrict__ attnb) {
  __shared__ char smem[65536];  // buf b at b*32768: Kt 16KB + Vts 16KB
  const int tid = threadIdx.x;
  const int w = tid >> 6, l = tid & 63;
  const int quad = l >> 4, l15 = l & 15;

  // XCD swizzle: same-bh blocks share lb%8 (one XCD, co-resident in dispatch order)
  const int lb = blockIdx.x + (blockIdx.y << 3);  // gridDim.x = 8
  const int bh = ((lb & 7) << 3) + ((lb >> 3) & 7);
  const int qt0 = (lb >> 6) * 256;

  const u16* Kbase = Kb + (size_t)bh * SEQ * HD;
  const u16* Vbase = Vtb + (size_t)bh * HD * SEQ;

  // Q fragments (B-operand layout: n=lane&15, k=quad*8+j); wave owns 32 rows
  short8 qf[2][2];
#pragma unroll
  for (int rt = 0; rt < 2; rt++) {
    int qrow = qt0 + w * 32 + rt * 16 + l15;
#pragma unroll
    for (int ks = 0; ks < 2; ks++)
      qf[rt][ks] = *(const short8*)(Qb + ((size_t)bh * SEQ + qrow) * HD + ks * 32 + quad * 8);
  }

  floatx4 O[2][4] = {};      // O^T: row=d=dt*16+quad*4+reg, col=q=rt*16+l15
  floatx4 sumacc[2] = {};

  union { u16 h[8]; short8 v; } onesu;
#pragma unroll
  for (int z = 0; z < 8; z++) onesu.h[z] = 0x3F80;
  const short8 ones = onesu.v;

  auto stage = [&](int n0, char* base) {
#pragma unroll
    for (int rnd = 0; rnd < 2; rnd++) {
      int ci = rnd * 512 + tid;
      int r = ci >> 3, pos = ci & 7;
      int c = pos ^ ((r & 7) ^ ((r >> 1) & 4));
      gload16(Kbase + (size_t)(n0 + r) * HD + c * 8, base + ci * 16);
    }
#pragma unroll
    for (int rnd = 0; rnd < 2; rnd++) {
      int ci = rnd * 512 + tid;
      int r = ci >> 4, pos = ci & 15;
      int c = pos ^ (r & 15);
      gload16(Vbase + (size_t)r * SEQ + n0 + c * 8, base + 16384 + ci * 16);
    }
  };

  stage(0, smem);
  __syncthreads();

  for (int kt = 0; kt < 16; kt++) {
    char* cur = smem + (kt & 1) * 32768;
    if (kt < 15) stage((kt + 1) * 128, smem + ((kt + 1) & 1) * 32768);

    char* KtC = cur;
    char* VtsC = cur + 16384;
#pragma unroll
    for (int p = 0; p < 4; p++) {
      // S^T tiles (permuted kcol rows)
      floatx4 s[2][2];
#pragma unroll
      for (int t = 0; t < 2; t++) {
        int rho = p * 32 + (l15 >> 2) * 8 + t * 4 + (l15 & 3);
        int g = (rho & 7) ^ ((rho >> 1) & 4);
        short8 kf0 = *(short8*)(KtC + rho * 128 + ((0 + quad) ^ g) * 16);
        short8 kf1 = *(short8*)(KtC + rho * 128 + ((4 + quad) ^ g) * 16);
#pragma unroll
        for (int rt = 0; rt < 2; rt++) {
          floatx4 z = {};
          z = __builtin_amdgcn_mfma_f32_16x16x32_bf16(kf0, qf[rt][0], z, 0, 0, 0);
          z = __builtin_amdgcn_mfma_f32_16x16x32_bf16(kf1, qf[rt][1], z, 0, 0, 0);
          s[t][rt] = z;
        }
      }
      // P = 2^S, trunc-pack to bf16 via v_perm; row sums via ones-MFMA
      short8 pf[2];
#pragma unroll
      for (int rt = 0; rt < 2; rt++) {
        union { u32 d[4]; short8 v; } pu;
#pragma unroll
        for (int t = 0; t < 2; t++) {
          float e0 = __builtin_amdgcn_exp2f(s[t][rt][0]);
          float e1 = __builtin_amdgcn_exp2f(s[t][rt][1]);
          float e2 = __builtin_amdgcn_exp2f(s[t][rt][2]);
          float e3 = __builtin_amdgcn_exp2f(s[t][rt][3]);
          pu.d[t * 2 + 0] = __builtin_amdgcn_perm(
              __builtin_bit_cast(u32, e1), __builtin_bit_cast(u32, e0), 0x07060302u);
          pu.d[t * 2 + 1] = __builtin_amdgcn_perm(
              __builtin_bit_cast(u32, e3), __builtin_bit_cast(u32, e2), 0x07060302u);
        }
        pf[rt] = pu.v;
        sumacc[rt] = __builtin_amdgcn_mfma_f32_16x16x32_bf16(ones, pf[rt], sumacc[rt], 0, 0, 0);
      }
      // O^T += V^T . P^T
#pragma unroll
      for (int dt = 0; dt < 4; dt++) {
        int rv = dt * 16 + l15;
        short8 vf = *(short8*)(VtsC + rv * 256 + ((p * 4 + quad) ^ (rv & 15)) * 16);
#pragma unroll
        for (int rt = 0; rt < 2; rt++)
          O[rt][dt] = __builtin_amdgcn_mfma_f32_16x16x32_bf16(vf, pf[rt], O[rt][dt], 0, 0, 0);
      }
    }
    __syncthreads();
  }

  float inv[2];
#pragma unroll
  for (int rt = 0; rt < 2; rt++) inv[rt] = 1.f / sumacc[rt][0];

  // epilogue: O^T -> LDS transpose (144B row stride, 256 rows = 36KB) -> coalesced
#pragma unroll
  for (int rt = 0; rt < 2; rt++)
#pragma unroll
    for (int dt = 0; dt < 4; dt++) {
      union { u16 h[4]; short4_t v; } pk;
#pragma unroll
      for (int r = 0; r < 4; r++) pk.h[r] = f2bf(O[rt][dt][r] * inv[rt]);
      *(short4_t*)(smem + (w * 32 + rt * 16 + l15) * 144 + (dt * 16 + quad * 4) * 2) = pk.v;
    }
  __syncthreads();
  {
    const int b = bh >> 4, h = bh & 15;
    int row = tid >> 1;      // 512 threads: 256 rows x 2 halves in one pass
    int half = tid & 1;
    u16* gp = attnb + ((size_t)(b * SEQ + qt0 + row)) * CDIM + h * 64 + half * 32;
    char* lp = smem + row * 144 + half * 64;
#pragma unroll
    for (int c = 0; c < 4; c++)
      *(short8*)(gp + c * 8) = *(short8*)(lp + c * 16);
  }
}

extern "C" void kernel_launch(void* const* d_in, const int* in_sizes, int n_in,
                              void* d_out, int out_size, void* d_ws, size_t ws_size,
                              hipStream_t stream) {
  const float* x = (const float*)d_in[0];
  const float* Wqkv = (const float*)d_in[1];
  const float* Wproj = (const float*)d_in[2];
  const float* bproj = (const float*)d_in[3];
  float* out = (float*)d_out;

  u16* xb = (u16*)d_ws;
  u16* wqkvT = xb + (size_t)8388608;
  u16* wprojT = wqkvT + (size_t)3145728;
  u16* qb = wprojT + (size_t)1048576;
  u16* kb = qb + (size_t)8388608;
  u16* vtb = kb + (size_t)8388608;
  u16* attnb = xb;  // xb dead after gemm_qkv

  cvt_x_kernel<<<4096, 256, 0, stream>>>(x, xb);
  transpose_w<<<dim3(96, 32), 256, 0, stream>>>(Wqkv, wqkvT, 1024, 3072);
  transpose_w<<<dim3(32, 32), 256, 0, stream>>>(Wproj, wprojT, 1024, 1024);
  gemm_qkv<<<dim3(32, 12), 512, 0, stream>>>(xb, wqkvT, qb, kb, vtb);
  attn_kernel<<<dim3(8, 64), 512, 0, stream>>>(qb, kb, vtb, attnb);
  gemm_proj<<<dim3(64, 8), 256, 0, stream>>>(attnb, wprojT, bproj, out);
}

// Round 5
// 244.207 us; speedup vs baseline: 1.1659x; 1.1659x over previous
//
#include <hip/hip_runtime.h>
#include <hip/hip_bf16.h>

typedef __attribute__((ext_vector_type(8))) short short8;
typedef __attribute__((ext_vector_type(4))) short short4_t;
typedef __attribute__((ext_vector_type(4))) float floatx4;
typedef unsigned short u16;
typedef unsigned int u32;

#define SEQ 2048
#define NH 16
#define HD 64
#define CDIM 1024
#define MTOT 8192

// RNE fp32 -> bf16
__device__ __forceinline__ u16 f2bf(float f) {
  u32 u = __builtin_bit_cast(u32, f);
  u32 r = u + 0x7FFFu + ((u >> 16) & 1u);
  return (u16)(r >> 16);
}

__device__ __forceinline__ void gload16(const void* g, void* l) {
  __builtin_amdgcn_global_load_lds(
      (const __attribute__((address_space(1))) u32*)g,
      (__attribute__((address_space(3))) u32*)l, 16, 0, 0);
}

// ---- prep: cvt x (fp32->bf16) + transpose both W (fused: 6->4 launches) ----
// blocks [0,4096): cvt_x (8 elems/thread)
// blocks [4096,7168): transpose Wqkv [1024][3072] -> [3072][1024] bf16
// blocks [7168,8192): transpose Wproj [1024][1024] -> [1024][1024] bf16
__global__ void prep_kernel(const float* __restrict__ x, u16* __restrict__ xb,
                            const float* __restrict__ Wqkv, u16* __restrict__ wqkvT,
                            const float* __restrict__ Wproj, u16* __restrict__ wprojT) {
  __shared__ float t[32][33];
  const int bid = blockIdx.x;
  if (bid < 4096) {
    size_t i = (size_t)bid * 256 + threadIdx.x;
    const float4* xv = (const float4*)x;
    float4 a = xv[2 * i], c = xv[2 * i + 1];
    union { u16 h[8]; short8 v; } u;
    u.h[0] = f2bf(a.x); u.h[1] = f2bf(a.y); u.h[2] = f2bf(a.z); u.h[3] = f2bf(a.w);
    u.h[4] = f2bf(c.x); u.h[5] = f2bf(c.y); u.h[6] = f2bf(c.z); u.h[7] = f2bf(c.w);
    *(short8*)(xb + 8 * i) = u.v;
    return;
  }
  const float* w; u16* wt; int K = 1024, N, n0, k0;
  if (bid < 7168) {
    int b = bid - 4096;  // 96 x 32
    w = Wqkv; wt = wqkvT; N = 3072;
    n0 = (b % 96) * 32; k0 = (b / 96) * 32;
  } else {
    int b = bid - 7168;  // 32 x 32
    w = Wproj; wt = wprojT; N = 1024;
    n0 = (b % 32) * 32; k0 = (b / 32) * 32;
  }
  int tr = threadIdx.x >> 5, tc = threadIdx.x & 31;
#pragma unroll
  for (int i = 0; i < 4; i++) {
    int r = tr + i * 8;
    t[r][tc] = w[(size_t)(k0 + r) * N + n0 + tc];
  }
  __syncthreads();
#pragma unroll
  for (int i = 0; i < 4; i++) {
    int r = tr + i * 8;
    wt[(size_t)(n0 + r) * K + k0 + tc] = f2bf(t[tc][r]);
  }
}

// ------------- 128x128x64 bf16 MFMA GEMM (verified m97-structure) -------------
// R4 post-mortem: 256^2 8-phase port regressed (1 blk/CU -> 384-block grid
// imbalance + L2-BW starvation at 52 B/cyc/CU + lockstep phases). Reverted to
// this verified structure (4 blocks/CU by VGPR/LDS, ~19 B/cyc/CU L2 demand).
__global__ __launch_bounds__(256, 2) void gemm_qkv(
    const u16* __restrict__ A, const u16* __restrict__ BT,
    u16* __restrict__ qb, u16* __restrict__ kb, u16* __restrict__ vtb) {
  __shared__ u16 Ab[128 * 64];
  __shared__ u16 Bb[128 * 64];
  const int tid = threadIdx.x;
  const int w = tid >> 6, l = tid & 63;
  const int quad = l >> 4, l15 = l & 15;
  const int m0 = blockIdx.x * 128, n0 = blockIdx.y * 128;
  const int wr = w >> 1, wc = w & 1;

  floatx4 acc[4][4] = {};

  for (int k0 = 0; k0 < 1024; k0 += 64) {
    __syncthreads();
#pragma unroll
    for (int rnd = 0; rnd < 4; rnd++) {
      int ci = rnd * 256 + tid;
      int r = ci >> 3, pos = ci & 7;
      int c = pos ^ (r & 7);
      gload16(A + (size_t)(m0 + r) * 1024 + k0 + c * 8, (char*)Ab + ci * 16);
      gload16(BT + (size_t)(n0 + r) * 1024 + k0 + c * 8, (char*)Bb + ci * 16);
    }
    __syncthreads();
    short8 af[4][2], bf[4][2];
#pragma unroll
    for (int t = 0; t < 4; t++) {
      int ra = wr * 64 + t * 16 + l15;
      int ga = ra & 7;
#pragma unroll
      for (int ks = 0; ks < 2; ks++)
        af[t][ks] = *(short8*)((char*)Ab + ra * 128 + ((ks * 4 + quad) ^ ga) * 16);
      int rb = wc * 64 + t * 16 + l15;
      int gb = rb & 7;
#pragma unroll
      for (int ks = 0; ks < 2; ks++)
        bf[t][ks] = *(short8*)((char*)Bb + rb * 128 + ((ks * 4 + quad) ^ gb) * 16);
    }
#pragma unroll
    for (int ks = 0; ks < 2; ks++)
#pragma unroll
      for (int i = 0; i < 4; i++)
#pragma unroll
        for (int j = 0; j < 4; j++)
          acc[i][j] = __builtin_amdgcn_mfma_f32_16x16x32_bf16(af[i][ks], bf[j][ks], acc[i][j], 0, 0, 0);
  }

  // epilogue: q pre-scaled by 0.125*log2(e) (exp2 folding), k -> [bh][n][d];
  // v -> transposed [bh][d][n]
#pragma unroll
  for (int i = 0; i < 4; i++)
#pragma unroll
    for (int j = 0; j < 4; j++)
#pragma unroll
      for (int r = 0; r < 4; r++) {
        int m = m0 + wr * 64 + i * 16 + quad * 4 + r;
        int c = n0 + wc * 64 + j * 16 + l15;
        int b = m >> 11, n = m & 2047;
        int t = c >> 10, rem = c & 1023;
        int h = rem >> 6, d = rem & 63;
        int bh = b * NH + h;
        if (t == 0)      qb[((size_t)bh * SEQ + n) * HD + d] = f2bf(acc[i][j][r] * 0.18033688011112042f);
        else if (t == 1) kb[((size_t)bh * SEQ + n) * HD + d] = f2bf(acc[i][j][r]);
        else             vtb[((size_t)bh * HD + d) * SEQ + n] = f2bf(acc[i][j][r]);
      }
}

__global__ __launch_bounds__(256, 2) void gemm_proj(
    const u16* __restrict__ A, const u16* __restrict__ BT,
    const float* __restrict__ bias, float* __restrict__ out) {
  __shared__ u16 Ab[128 * 64];
  __shared__ u16 Bb[128 * 64];
  const int tid = threadIdx.x;
  const int w = tid >> 6, l = tid & 63;
  const int quad = l >> 4, l15 = l & 15;
  const int m0 = blockIdx.x * 128, n0 = blockIdx.y * 128;
  const int wr = w >> 1, wc = w & 1;

  floatx4 acc[4][4] = {};

  for (int k0 = 0; k0 < 1024; k0 += 64) {
    __syncthreads();
#pragma unroll
    for (int rnd = 0; rnd < 4; rnd++) {
      int ci = rnd * 256 + tid;
      int r = ci >> 3, pos = ci & 7;
      int c = pos ^ (r & 7);
      gload16(A + (size_t)(m0 + r) * 1024 + k0 + c * 8, (char*)Ab + ci * 16);
      gload16(BT + (size_t)(n0 + r) * 1024 + k0 + c * 8, (char*)Bb + ci * 16);
    }
    __syncthreads();
    short8 af[4][2], bf[4][2];
#pragma unroll
    for (int t = 0; t < 4; t++) {
      int ra = wr * 64 + t * 16 + l15;
      int ga = ra & 7;
#pragma unroll
      for (int ks = 0; ks < 2; ks++)
        af[t][ks] = *(short8*)((char*)Ab + ra * 128 + ((ks * 4 + quad) ^ ga) * 16);
      int rb = wc * 64 + t * 16 + l15;
      int gb = rb & 7;
#pragma unroll
      for (int ks = 0; ks < 2; ks++)
        bf[t][ks] = *(short8*)((char*)Bb + rb * 128 + ((ks * 4 + quad) ^ gb) * 16);
    }
#pragma unroll
    for (int ks = 0; ks < 2; ks++)
#pragma unroll
      for (int i = 0; i < 4; i++)
#pragma unroll
        for (int j = 0; j < 4; j++)
          acc[i][j] = __builtin_amdgcn_mfma_f32_16x16x32_bf16(af[i][ks], bf[j][ks], acc[i][j], 0, 0, 0);
  }

#pragma unroll
  for (int i = 0; i < 4; i++)
#pragma unroll
    for (int j = 0; j < 4; j++)
#pragma unroll
      for (int r = 0; r < 4; r++) {
        int m = m0 + wr * 64 + i * 16 + quad * 4 + r;
        int c = n0 + wc * 64 + j * 16 + l15;
        out[(size_t)m * CDIM + c] = acc[i][j][r] + bias[c];
      }
}

// ---- flash attention v5 (verified 72.3us): 8 waves x 32 Q-rows, 16 waves/CU ----
__global__ __launch_bounds__(512, 4) void attn_kernel(
    const u16* __restrict__ Qb, const u16* __restrict__ Kb,
    const u16* __restrict__ Vtb, u16* __restrict__ attnb) {
  __shared__ char smem[65536];  // buf b at b*32768: Kt 16KB + Vts 16KB
  const int tid = threadIdx.x;
  const int w = tid >> 6, l = tid & 63;
  const int quad = l >> 4, l15 = l & 15;

  // XCD swizzle: same-bh blocks share lb%8 (one XCD, co-resident in dispatch order)
  const int lb = blockIdx.x + (blockIdx.y << 3);  // gridDim.x = 8
  const int bh = ((lb & 7) << 3) + ((lb >> 3) & 7);
  const int qt0 = (lb >> 6) * 256;

  const u16* Kbase = Kb + (size_t)bh * SEQ * HD;
  const u16* Vbase = Vtb + (size_t)bh * HD * SEQ;

  // Q fragments (B-operand layout: n=lane&15, k=quad*8+j); wave owns 32 rows
  short8 qf[2][2];
#pragma unroll
  for (int rt = 0; rt < 2; rt++) {
    int qrow = qt0 + w * 32 + rt * 16 + l15;
#pragma unroll
    for (int ks = 0; ks < 2; ks++)
      qf[rt][ks] = *(const short8*)(Qb + ((size_t)bh * SEQ + qrow) * HD + ks * 32 + quad * 8);
  }

  floatx4 O[2][4] = {};      // O^T: row=d=dt*16+quad*4+reg, col=q=rt*16+l15
  floatx4 sumacc[2] = {};

  union { u16 h[8]; short8 v; } onesu;
#pragma unroll
  for (int z = 0; z < 8; z++) onesu.h[z] = 0x3F80;
  const short8 ones = onesu.v;

  auto stage = [&](int n0, char* base) {
#pragma unroll
    for (int rnd = 0; rnd < 2; rnd++) {
      int ci = rnd * 512 + tid;
      int r = ci >> 3, pos = ci & 7;
      int c = pos ^ ((r & 7) ^ ((r >> 1) & 4));
      gload16(Kbase + (size_t)(n0 + r) * HD + c * 8, base + ci * 16);
    }
#pragma unroll
    for (int rnd = 0; rnd < 2; rnd++) {
      int ci = rnd * 512 + tid;
      int r = ci >> 4, pos = ci & 15;
      int c = pos ^ (r & 15);
      gload16(Vbase + (size_t)r * SEQ + n0 + c * 8, base + 16384 + ci * 16);
    }
  };

  stage(0, smem);
  __syncthreads();

  for (int kt = 0; kt < 16; kt++) {
    char* cur = smem + (kt & 1) * 32768;
    if (kt < 15) stage((kt + 1) * 128, smem + ((kt + 1) & 1) * 32768);

    char* KtC = cur;
    char* VtsC = cur + 16384;
#pragma unroll
    for (int p = 0; p < 4; p++) {
      // S^T tiles (permuted kcol rows)
      floatx4 s[2][2];
#pragma unroll
      for (int t = 0; t < 2; t++) {
        int rho = p * 32 + (l15 >> 2) * 8 + t * 4 + (l15 & 3);
        int g = (rho & 7) ^ ((rho >> 1) & 4);
        short8 kf0 = *(short8*)(KtC + rho * 128 + ((0 + quad) ^ g) * 16);
        short8 kf1 = *(short8*)(KtC + rho * 128 + ((4 + quad) ^ g) * 16);
#pragma unroll
        for (int rt = 0; rt < 2; rt++) {
          floatx4 z = {};
          z = __builtin_amdgcn_mfma_f32_16x16x32_bf16(kf0, qf[rt][0], z, 0, 0, 0);
          z = __builtin_amdgcn_mfma_f32_16x16x32_bf16(kf1, qf[rt][1], z, 0, 0, 0);
          s[t][rt] = z;
        }
      }
      // P = 2^S, trunc-pack to bf16 via v_perm; row sums via ones-MFMA
      short8 pf[2];
#pragma unroll
      for (int rt = 0; rt < 2; rt++) {
        union { u32 d[4]; short8 v; } pu;
#pragma unroll
        for (int t = 0; t < 2; t++) {
          float e0 = __builtin_amdgcn_exp2f(s[t][rt][0]);
          float e1 = __builtin_amdgcn_exp2f(s[t][rt][1]);
          float e2 = __builtin_amdgcn_exp2f(s[t][rt][2]);
          float e3 = __builtin_amdgcn_exp2f(s[t][rt][3]);
          pu.d[t * 2 + 0] = __builtin_amdgcn_perm(
              __builtin_bit_cast(u32, e1), __builtin_bit_cast(u32, e0), 0x07060302u);
          pu.d[t * 2 + 1] = __builtin_amdgcn_perm(
              __builtin_bit_cast(u32, e3), __builtin_bit_cast(u32, e2), 0x07060302u);
        }
        pf[rt] = pu.v;
        sumacc[rt] = __builtin_amdgcn_mfma_f32_16x16x32_bf16(ones, pf[rt], sumacc[rt], 0, 0, 0);
      }
      // O^T += V^T . P^T
#pragma unroll
      for (int dt = 0; dt < 4; dt++) {
        int rv = dt * 16 + l15;
        short8 vf = *(short8*)(VtsC + rv * 256 + ((p * 4 + quad) ^ (rv & 15)) * 16);
#pragma unroll
        for (int rt = 0; rt < 2; rt++)
          O[rt][dt] = __builtin_amdgcn_mfma_f32_16x16x32_bf16(vf, pf[rt], O[rt][dt], 0, 0, 0);
      }
    }
    __syncthreads();
  }

  float inv[2];
#pragma unroll
  for (int rt = 0; rt < 2; rt++) inv[rt] = 1.f / sumacc[rt][0];

  // epilogue: O^T -> LDS transpose (144B row stride, 256 rows = 36KB) -> coalesced
#pragma unroll
  for (int rt = 0; rt < 2; rt++)
#pragma unroll
    for (int dt = 0; dt < 4; dt++) {
      union { u16 h[4]; short4_t v; } pk;
#pragma unroll
      for (int r = 0; r < 4; r++) pk.h[r] = f2bf(O[rt][dt][r] * inv[rt]);
      *(short4_t*)(smem + (w * 32 + rt * 16 + l15) * 144 + (dt * 16 + quad * 4) * 2) = pk.v;
    }
  __syncthreads();
  {
    const int b = bh >> 4, h = bh & 15;
    int row = tid >> 1;      // 512 threads: 256 rows x 2 halves in one pass
    int half = tid & 1;
    u16* gp = attnb + ((size_t)(b * SEQ + qt0 + row)) * CDIM + h * 64 + half * 32;
    char* lp = smem + row * 144 + half * 64;
#pragma unroll
    for (int c = 0; c < 4; c++)
      *(short8*)(gp + c * 8) = *(short8*)(lp + c * 16);
  }
}

extern "C" void kernel_launch(void* const* d_in, const int* in_sizes, int n_in,
                              void* d_out, int out_size, void* d_ws, size_t ws_size,
                              hipStream_t stream) {
  const float* x = (const float*)d_in[0];
  const float* Wqkv = (const float*)d_in[1];
  const float* Wproj = (const float*)d_in[2];
  const float* bproj = (const float*)d_in[3];
  float* out = (float*)d_out;

  u16* xb = (u16*)d_ws;
  u16* wqkvT = xb + (size_t)8388608;
  u16* wprojT = wqkvT + (size_t)3145728;
  u16* qb = wprojT + (size_t)1048576;
  u16* kb = qb + (size_t)8388608;
  u16* vtb = kb + (size_t)8388608;
  u16* attnb = xb;  // xb dead after gemm_qkv

  prep_kernel<<<8192, 256, 0, stream>>>(x, xb, Wqkv, wqkvT, Wproj, wprojT);
  gemm_qkv<<<dim3(64, 24), 256, 0, stream>>>(xb, wqkvT, qb, kb, vtb);
  attn_kernel<<<dim3(8, 64), 512, 0, stream>>>(qb, kb, vtb, attnb);
  gemm_proj<<<dim3(64, 8), 256, 0, stream>>>(attnb, wprojT, bproj, out);
}